// Round 15
// baseline (249.656 us; speedup 1.0000x reference)
//
#include <hip/hip_runtime.h>
#include <cmath>

typedef float    float4_t __attribute__((ext_vector_type(4)));
typedef float    f32x16   __attribute__((ext_vector_type(16)));
typedef __bf16   bf16x8   __attribute__((ext_vector_type(8)));
typedef unsigned uint4_v  __attribute__((ext_vector_type(4)));
typedef unsigned short u16;

// V^T row stride (u16 units): 2048 + 64 pad (keeps 16B alignment: 4224B rows).
#define VSTR 2112

// fp32 -> bf16 round-to-nearest-even
__device__ __forceinline__ u16 f2bf(float f) {
    unsigned u = __float_as_uint(f);
    u += 0x7fffu + ((u >> 16) & 1u);
    return (u16)(u >> 16);
}

// v_cvt_pk_bf16_f32: lo = bf16(a), hi = bf16(b)
__device__ __forceinline__ unsigned cvtpk(float a, float b) {
    unsigned r;
    asm("v_cvt_pk_bf16_f32 %0, %1, %2" : "=v"(r) : "v"(a), "v"(b));
    return r;
}
// v_permlane32_swap_b32: a[32..63] <-> b[0..31]
__device__ __forceinline__ void pl32swap(unsigned& a, unsigned& b) {
    asm volatile("v_permlane32_swap_b32 %0, %1" : "+v"(a), "+v"(b));
}

// async global->LDS, 16B per lane. LDS dest must be wave-uniform base + lane*16.
#define GLOAD_LDS16(g, l)                                              \
    __builtin_amdgcn_global_load_lds(                                  \
        (__attribute__((address_space(1))) void*)(g),                  \
        (__attribute__((address_space(3))) void*)(l), 16, 0, 0)

// Chunk swizzle: global chunk c of row r stored at LDS chunk (c + (r>>1))&3.
// Staging picks global chunk (cs - (r>>1))&3 for LDS slot cs; frag reads use
// chunk ((ch + (r>>1))&3). Keeps b128 frag reads near the free 2-way tier.
__device__ __forceinline__ int sw_st(int cs, int row) { return ((cs - (row >> 1)) & 3) * 8; }
__device__ __forceinline__ int sw_rd(int ch, int row) { return (((ch + (row >> 1)) & 3)) * 8; }

// ---------------- merged cast fp32 -> bf16 for all 5 tensors ----------------
__global__ __launch_bounds__(256) void cast_all(const float* __restrict__ x,
                                                const float* __restrict__ wq,
                                                const float* __restrict__ wk,
                                                const float* __restrict__ wv,
                                                const float* __restrict__ wo,
                                                u16* __restrict__ xb, u16* __restrict__ wqb,
                                                u16* __restrict__ wkb, u16* __restrict__ wvb,
                                                u16* __restrict__ wob) {
    const int b = blockIdx.x;
    const float* src;
    u16* dst;
    int i;
    if (b < 4096)      { src = x;  dst = xb;  i = b * 256 + threadIdx.x; }
    else if (b < 8192) { src = wq; dst = wqb; i = (b - 4096) * 256 + threadIdx.x; }
    else if (b < 8448) { src = wk; dst = wkb; i = (b - 8192) * 256 + threadIdx.x; }
    else if (b < 8704) { src = wv; dst = wvb; i = (b - 8448) * 256 + threadIdx.x; }
    else               { src = wo; dst = wob; i = (b - 8704) * 256 + threadIdx.x; }
    float4 f = ((const float4*)src)[i];
    ushort4 r;
    r.x = f2bf(f.x); r.y = f2bf(f.y); r.z = f2bf(f.z); r.w = f2bf(f.w);
    ((ushort4*)dst)[i] = r;
}

// ================= GEMM core (A @ B^T, 64x128 tile, BK=64, swizzled) ========
// 2-phase double-buffered staging; ONE barrier per K-step. 48KB LDS, 4 waves.
template <typename EPI>
__device__ __forceinline__ void gemm_core(const u16* __restrict__ A,
                                          const u16* __restrict__ B,
                                          int K, int bm, int bn, EPI epi) {
    __shared__ __align__(16) u16 As[2][2 * 64 * 32];
    __shared__ __align__(16) u16 Bs[2][2 * 128 * 32];
    const int tid  = threadIdx.x;
    const int lane = tid & 63, wave = tid >> 6;
    const int quad = lane >> 4, l16 = lane & 15;

    float4_t acc[4][2] = {};

    auto stage = [&](int k0, int buf) {
#pragma unroll
        for (int i = 0; i < 2; ++i) {
            const int slot = i * 256 + tid;
            const int ksb = slot >> 8, win = slot & 255;
            const int row = win >> 2;
            GLOAD_LDS16(A + (size_t)(bm + row) * K + k0 + ksb * 32 + sw_st(win & 3, row),
                        &As[buf][slot * 8]);
        }
#pragma unroll
        for (int i = 0; i < 4; ++i) {
            const int slot = i * 256 + tid;
            const int ksb = slot >> 9, win = slot & 511;
            const int row = win >> 2;
            GLOAD_LDS16(B + (size_t)(bn + row) * K + k0 + ksb * 32 + sw_st(win & 3, row),
                        &Bs[buf][slot * 8]);
        }
    };

    stage(0, 0);
    __syncthreads();
    int cur = 0;
    for (int k0 = 0; k0 < K; k0 += 64) {
        if (k0 + 64 < K) stage(k0 + 64, cur ^ 1);

        bf16x8 af[2][4], bfr[2][2];
#pragma unroll
        for (int ksb = 0; ksb < 2; ++ksb) {
#pragma unroll
            for (int mi = 0; mi < 4; ++mi) {
                const int rw = mi * 16 + l16;
                af[ksb][mi] = *(const bf16x8*)&As[cur][ksb * 2048 + rw * 32 + sw_rd(quad, rw)];
            }
#pragma unroll
            for (int ni = 0; ni < 2; ++ni) {
                const int rw = wave * 32 + ni * 16 + l16;
                bfr[ksb][ni] = *(const bf16x8*)&Bs[cur][ksb * 4096 + rw * 32 + sw_rd(quad, rw)];
            }
        }
#pragma unroll
        for (int mi = 0; mi < 4; ++mi)
#pragma unroll
            for (int ni = 0; ni < 2; ++ni) {
                acc[mi][ni] = __builtin_amdgcn_mfma_f32_16x16x32_bf16(
                    af[0][mi], bfr[0][ni], acc[mi][ni], 0, 0, 0);
                acc[mi][ni] = __builtin_amdgcn_mfma_f32_16x16x32_bf16(
                    af[1][mi], bfr[1][ni], acc[mi][ni], 0, 0, 0);
            }
        __syncthreads();   // drains next-tile gload_lds (vmcnt) + read hazard
        cur ^= 1;
    }

#pragma unroll
    for (int mi = 0; mi < 4; ++mi) {
        const int row = bm + mi * 16 + quad * 4;
#pragma unroll
        for (int ni = 0; ni < 2; ++ni) {
            const int col = bn + wave * 32 + ni * 16 + l16;
#pragma unroll
            for (int r = 0; r < 4; ++r) epi(row + r, col, acc[mi][ni][r]);
        }
    }
}

// Fused QKV projection: B rows = [Wq(2048) | Wk(128) | Wv(128)], N=2304.
// Q gets (1/sqrt(128))*log2(e) folded in (attention uses exp2).
__global__ __launch_bounds__(256) void gemm_qkv(const u16* __restrict__ A,
                                                const u16* __restrict__ B,
                                                u16* __restrict__ qb,
                                                u16* __restrict__ kb,
                                                u16* __restrict__ vtb) {
    gemm_core(A, B, 2048, blockIdx.x * 64, blockIdx.y * 128,
              [=](int row, int col, float v) {
                  if (col < 2048)
                      qb[(size_t)row * 2048 + col] = f2bf(v * 0.1275174313451427f);
                  else if (col < 2176)
                      kb[(size_t)row * 128 + (col - 2048)] = f2bf(v);
                  else
                      vtb[(size_t)(col - 2176) * VSTR + row] = f2bf(v);
              });
}

__global__ __launch_bounds__(256) void gemm_out(const u16* __restrict__ A,
                                                const u16* __restrict__ B,
                                                float* __restrict__ C) {
    gemm_core(A, B, 2048, blockIdx.x * 64, blockIdx.y * 128,
              [=](int row, int col, float v) {
                  C[(size_t)row * 2048 + col] = v;
              });
}

// ---------------- MQA flash attention, split-K (2 or 4), 32 keys/step -------
// r13 post-mortem: occupancy was GRID-capped (512 blocks = 2/CU) — LDS/VGPR
// shrink changed nothing (55.8us, MfmaUtil 24%, Occ 17%). Fix: split-K=4 ->
// 1024 blocks x 4 waves = 4096 waves = 4 waves/SIMD, 4 independent barrier
// groups/CU. Needs 3 extra 16MB fp32 partials (~91MB ws): launcher guards
// ws_size and falls back to split-K=2 (identical to r13's measured config).
// Structure otherwise r13: 32x32x16 swapped QK^T; P in registers via
// cvt_pk + permlane32_swap (T12); K+V double-buffered LDS (32KB); ONE
// barrier/step. Deferred softmax: P = exp2(s) (Q pre-scaled); fp32 partials
// + Lsum, normalized in combine.
__global__ __launch_bounds__(256, 4) void mqa_attn(const u16* __restrict__ Q,
                                                   const u16* __restrict__ Kmat,
                                                   const u16* __restrict__ Vt,
                                                   float* __restrict__ Oacc0,
                                                   float* __restrict__ OaccHi,
                                                   float* __restrict__ Lsum,
                                                   int nkeys) {
    __shared__ __align__(16) u16 Ks[2][4 * 32 * 32];  // [buf][d-chunk][key32][32 d] 8KB/buf
    __shared__ __align__(16) u16 Vts[2][128 * 32];    // [buf][d128][32 keys]       8KB/buf
    const int tid  = threadIdx.x;
    const int wave = tid >> 6, lane = tid & 63;
    const int l31 = lane & 31, hi = lane >> 5;
    const int h     = blockIdx.y;
    const int ksp   = blockIdx.z;
    const int qbase = blockIdx.x * 128 + wave * 32;
    const int kbase = ksp * nkeys;
    const int nsteps = nkeys >> 5;

    // Q as B-operand frags: lane holds Q[q = l31][c*16 + hi*8 + j]
    bf16x8 qf[8];
    {
        const u16* qptr = Q + (size_t)(qbase + l31) * 2048 + h * 128 + hi * 8;
#pragma unroll
        for (int c = 0; c < 8; ++c) qf[c] = *(const bf16x8*)(qptr + c * 16);
    }

    f32x16 acc[4];
#pragma unroll
    for (int dt = 0; dt < 4; ++dt) acc[dt] = (f32x16)(0.0f);
    float lsum = 0.f;

    auto stage = [&](int s, int buf) {
        const int k0 = kbase + s * 32;
        // K tile: 512 slots of 16B (kb4=slot>>7, row=(slot&127)>>2, cs=slot&3)
#pragma unroll
        for (int i = 0; i < 2; ++i) {
            const int slot = i * 256 + tid;
            const int kb4 = slot >> 7, win = slot & 127;
            const int row = win >> 2;
            GLOAD_LDS16(Kmat + (size_t)(k0 + row) * 128 + kb4 * 32 + sw_st(win & 3, row),
                        &Ks[buf][slot * 8]);
        }
        // V^T tile: 512 slots (row=slot>>2 over 128 d, cs=slot&3 over 32 keys)
#pragma unroll
        for (int i = 0; i < 2; ++i) {
            const int slot = i * 256 + tid;
            const int row = slot >> 2;
            GLOAD_LDS16(Vt + (size_t)row * VSTR + k0 + sw_st(slot & 3, row),
                        &Vts[buf][slot * 8]);
        }
    };

    stage(0, 0);
    __syncthreads();
    int cur = 0;

    for (int s = 0; s < nsteps; ++s) {
        if (s < nsteps - 1) stage(s + 1, cur ^ 1);

        // ---- S^T = K Q^T: one 8-MFMA chain over the 32-key tile ----
        f32x16 sv = (f32x16)(0.0f);
#pragma unroll
        for (int c = 0; c < 8; ++c) {
            const int ch = (c & 1) * 2 + hi;
            bf16x8 kf = *(const bf16x8*)&Ks[cur][(c >> 1) * 1024 + l31 * 32 + sw_rd(ch, l31)];
            sv = __builtin_amdgcn_mfma_f32_32x32x16_bf16(kf, qf[c], sv, 0, 0, 0);
        }

        // ---- P = exp2(S) packed in-register -> PV A-frags ----
        // lane holds S^T[key=(r&3)+8*(r>>2)+4*hi][q=l31]
        bf16x8 pa[2];  // [key chunk of 16]
        {
            float e[16];
#pragma unroll
            for (int r = 0; r < 16; ++r) {
                e[r] = exp2f(sv[r]);
                lsum += e[r];
            }
#pragma unroll
            for (int half = 0; half < 2; ++half) {
                unsigned a0 = cvtpk(e[half * 8 + 0], e[half * 8 + 1]);
                unsigned a1 = cvtpk(e[half * 8 + 2], e[half * 8 + 3]);
                unsigned b0 = cvtpk(e[half * 8 + 4], e[half * 8 + 5]);
                unsigned b1 = cvtpk(e[half * 8 + 6], e[half * 8 + 7]);
                pl32swap(a0, b0);
                pl32swap(a1, b1);
                uint4_v w = {a0, a1, b0, b1};
                pa[half] = __builtin_bit_cast(bf16x8, w);
            }
        }

        // ---- O += P V : 8 MFMA, 4 independent dt chains ----
#pragma unroll
        for (int kc = 0; kc < 2; ++kc) {
            const int ch = kc * 2 + hi;
#pragma unroll
            for (int dt = 0; dt < 4; ++dt) {
                const int row = dt * 32 + l31;  // d row
                bf16x8 vf = *(const bf16x8*)&Vts[cur][row * 32 + sw_rd(ch, row)];
                acc[dt] = __builtin_amdgcn_mfma_f32_32x32x16_bf16(pa[kc], vf, acc[dt], 0, 0, 0);
            }
        }
        __syncthreads();   // drains next-tile gload_lds + this tile's reads
        cur ^= 1;
    }

    // ---- epilogue: unnormalized fp32 partials + per-row sums ----
    float lrow = lsum + __shfl_xor(lsum, 32);
    float* __restrict__ Op = ksp ? (OaccHi + (size_t)(ksp - 1) * (4u << 20)) : Oacc0;
    if (lane < 32) Lsum[(size_t)ksp * 32768 + h * 2048 + qbase + l31] = lrow;
#pragma unroll
    for (int dt = 0; dt < 4; ++dt)
#pragma unroll
        for (int r = 0; r < 16; ++r) {
            const int qloc = (r & 3) + 8 * (r >> 2) + 4 * hi;
            Op[((size_t)h * 2048 + qbase + qloc) * 128 + dt * 32 + l31] = acc[dt][r];
        }
}

// combine: attn[q][h*128+d] = sum_s(Os)/sum_s(Ls), bf16. One float4 per thread.
__global__ __launch_bounds__(256) void attn_combine(const float* __restrict__ O0,
                                                    const float* __restrict__ OHi,
                                                    const float* __restrict__ L,
                                                    u16* __restrict__ attn,
                                                    int nsplit) {
    const int f = blockIdx.x * 256 + threadIdx.x;  // [0, 1M)
    const int d4 = f & 31, h = (f >> 5) & 15, q = f >> 9;
    const int li = h * 2048 + q;
    float lt = L[li];
    for (int s = 1; s < nsplit; ++s) lt += L[(size_t)s * 32768 + li];
    const float inv = 1.0f / lt;
    const int oi = li * 32 + d4;
    float4 a = ((const float4*)O0)[oi];
    for (int s = 1; s < nsplit; ++s) {
        const float4 b = ((const float4*)(OHi + (size_t)(s - 1) * (4u << 20)))[oi];
        a.x += b.x; a.y += b.y; a.z += b.z; a.w += b.w;
    }
    ushort4 r;
    r.x = f2bf(a.x * inv);
    r.y = f2bf(a.y * inv);
    r.z = f2bf(a.z * inv);
    r.w = f2bf(a.w * inv);
    ((ushort4*)attn)[f] = r;
}

// ---------------- orchestration ----------------
extern "C" void kernel_launch(void* const* d_in, const int* in_sizes, int n_in,
                              void* d_out, int out_size, void* d_ws, size_t ws_size,
                              hipStream_t stream) {
    const float* x  = (const float*)d_in[0];
    const float* Wq = (const float*)d_in[1];
    const float* Wk = (const float*)d_in[2];
    const float* Wv = (const float*)d_in[3];
    const float* Wo = (const float*)d_in[4];
    float* out = (float*)d_out;

    // Wqb/Wkb/Wvb contiguous: together a 2304x2048 bf16 B matrix for gemm_qkv.
    // Overlays (stream-ordered, deterministic):
    //   Oacc0:  [0,16MB)   -- xb+Wqb dead after gemm_qkv
    //   OaccHi: after attn buffer (42.5MB) -- (nsplit-1) x 16MB partials
    //   Lsum:   after last partial. Peak: nsplit=2 -> ~59MB, nsplit=4 -> ~91MB.
    u16* ws   = (u16*)d_ws;
    u16* xb   = ws;                        // 2048x2048 bf16
    u16* Wqb  = xb  + (4 << 20);           // 2048x2048
    u16* Wkb  = Wqb + (4 << 20);           // 128x2048
    u16* Wvb  = Wkb + (256 << 10);         // 128x2048
    u16* Wob  = Wvb + (256 << 10);         // 2048x2048
    u16* qb   = Wob + (4 << 20);           // 2048x2048 (pre-scaled)
    u16* kb   = qb  + (4 << 20);           // 2048x128
    u16* vtb  = kb  + (256 << 10);         // 128xVSTR (V^T, padded rows)
    u16* attn = vtb + (512 << 10);         // 2048x2048 bf16
    float* Oacc0  = (float*)ws;            // 16 MB
    float* OaccHi = (float*)(attn + (4 << 20));   // (nsplit-1) x 16MB

    // split-K=4 doubles resident waves (grid 512->1024 blocks) but needs ~91MB
    // workspace; guard and fall back to the r13-measured split-K=2 layout.
    const int nsplit = (ws_size >= ((size_t)93 << 20)) ? 4 : 2;
    float* Lsum = OaccHi + (size_t)(nsplit - 1) * (4u << 20);  // nsplit x 32768 fp32

    cast_all<<<12800, 256, 0, stream>>>(x, Wq, Wk, Wv, Wo, xb, Wqb, Wkb, Wvb, Wob);

    gemm_qkv<<<dim3(32, 18), 256, 0, stream>>>(xb, Wqb, qb, kb, vtb);
    mqa_attn<<<dim3(16, 16, nsplit), 256, 0, stream>>>(qb, kb, vtb, Oacc0, OaccHi, Lsum,
                                                       2048 / nsplit);
    attn_combine<<<4096, 256, 0, stream>>>(Oacc0, OaccHi, Lsum, attn, nsplit);
    gemm_out<<<dim3(32, 16), 256, 0, stream>>>(attn, Wob, out);
}

// Round 19
// 217.669 us; speedup vs baseline: 1.1470x; 1.1470x over previous
//
#include <hip/hip_runtime.h>
#include <cmath>

typedef float    float4_t __attribute__((ext_vector_type(4)));
typedef float    f32x16   __attribute__((ext_vector_type(16)));
typedef __bf16   bf16x8   __attribute__((ext_vector_type(8)));
typedef unsigned uint4_v  __attribute__((ext_vector_type(4)));
typedef unsigned short u16;

// V^T row stride (u16 units): 2048 + 64 pad (keeps 16B alignment: 4224B rows).
#define VSTR 2112

// fp32 -> bf16 round-to-nearest-even
__device__ __forceinline__ u16 f2bf(float f) {
    unsigned u = __float_as_uint(f);
    u += 0x7fffu + ((u >> 16) & 1u);
    return (u16)(u >> 16);
}

// v_cvt_pk_bf16_f32: lo = bf16(a), hi = bf16(b)
__device__ __forceinline__ unsigned cvtpk(float a, float b) {
    unsigned r;
    asm("v_cvt_pk_bf16_f32 %0, %1, %2" : "=v"(r) : "v"(a), "v"(b));
    return r;
}
// v_permlane32_swap_b32: a[32..63] <-> b[0..31]
__device__ __forceinline__ void pl32swap(unsigned& a, unsigned& b) {
    asm volatile("v_permlane32_swap_b32 %0, %1" : "+v"(a), "+v"(b));
}

// async global->LDS, 16B per lane. LDS dest must be wave-uniform base + lane*16.
#define GLOAD_LDS16(g, l)                                              \
    __builtin_amdgcn_global_load_lds(                                  \
        (__attribute__((address_space(1))) void*)(g),                  \
        (__attribute__((address_space(3))) void*)(l), 16, 0, 0)

// Chunk swizzle: global chunk c of row r stored at LDS chunk (c + (r>>1))&3.
// Staging picks global chunk (cs - (r>>1))&3 for LDS slot cs; frag reads use
// chunk ((ch + (r>>1))&3). Keeps b128 frag reads near the free 2-way tier.
__device__ __forceinline__ int sw_st(int cs, int row) { return ((cs - (row >> 1)) & 3) * 8; }
__device__ __forceinline__ int sw_rd(int ch, int row) { return (((ch + (row >> 1)) & 3)) * 8; }

// ---------------- merged cast fp32 -> bf16 for all 5 tensors ----------------
__global__ __launch_bounds__(256) void cast_all(const float* __restrict__ x,
                                                const float* __restrict__ wq,
                                                const float* __restrict__ wk,
                                                const float* __restrict__ wv,
                                                const float* __restrict__ wo,
                                                u16* __restrict__ xb, u16* __restrict__ wqb,
                                                u16* __restrict__ wkb, u16* __restrict__ wvb,
                                                u16* __restrict__ wob) {
    const int b = blockIdx.x;
    const float* src;
    u16* dst;
    int i;
    if (b < 4096)      { src = x;  dst = xb;  i = b * 256 + threadIdx.x; }
    else if (b < 8192) { src = wq; dst = wqb; i = (b - 4096) * 256 + threadIdx.x; }
    else if (b < 8448) { src = wk; dst = wkb; i = (b - 8192) * 256 + threadIdx.x; }
    else if (b < 8704) { src = wv; dst = wvb; i = (b - 8448) * 256 + threadIdx.x; }
    else               { src = wo; dst = wob; i = (b - 8704) * 256 + threadIdx.x; }
    float4 f = ((const float4*)src)[i];
    ushort4 r;
    r.x = f2bf(f.x); r.y = f2bf(f.y); r.z = f2bf(f.z); r.w = f2bf(f.w);
    ((ushort4*)dst)[i] = r;
}

// ================= GEMM core (A @ B^T, 64x128 tile, BK=64, swizzled) ========
// 2-phase double-buffered staging; ONE barrier per K-step. 48KB LDS, 4 waves.
template <typename EPI>
__device__ __forceinline__ void gemm_core(const u16* __restrict__ A,
                                          const u16* __restrict__ B,
                                          int K, int bm, int bn, EPI epi) {
    __shared__ __align__(16) u16 As[2][2 * 64 * 32];
    __shared__ __align__(16) u16 Bs[2][2 * 128 * 32];
    const int tid  = threadIdx.x;
    const int lane = tid & 63, wave = tid >> 6;
    const int quad = lane >> 4, l16 = lane & 15;

    float4_t acc[4][2] = {};

    auto stage = [&](int k0, int buf) {
#pragma unroll
        for (int i = 0; i < 2; ++i) {
            const int slot = i * 256 + tid;
            const int ksb = slot >> 8, win = slot & 255;
            const int row = win >> 2;
            GLOAD_LDS16(A + (size_t)(bm + row) * K + k0 + ksb * 32 + sw_st(win & 3, row),
                        &As[buf][slot * 8]);
        }
#pragma unroll
        for (int i = 0; i < 4; ++i) {
            const int slot = i * 256 + tid;
            const int ksb = slot >> 9, win = slot & 511;
            const int row = win >> 2;
            GLOAD_LDS16(B + (size_t)(bn + row) * K + k0 + ksb * 32 + sw_st(win & 3, row),
                        &Bs[buf][slot * 8]);
        }
    };

    stage(0, 0);
    __syncthreads();
    int cur = 0;
    for (int k0 = 0; k0 < K; k0 += 64) {
        if (k0 + 64 < K) stage(k0 + 64, cur ^ 1);

        bf16x8 af[2][4], bfr[2][2];
#pragma unroll
        for (int ksb = 0; ksb < 2; ++ksb) {
#pragma unroll
            for (int mi = 0; mi < 4; ++mi) {
                const int rw = mi * 16 + l16;
                af[ksb][mi] = *(const bf16x8*)&As[cur][ksb * 2048 + rw * 32 + sw_rd(quad, rw)];
            }
#pragma unroll
            for (int ni = 0; ni < 2; ++ni) {
                const int rw = wave * 32 + ni * 16 + l16;
                bfr[ksb][ni] = *(const bf16x8*)&Bs[cur][ksb * 4096 + rw * 32 + sw_rd(quad, rw)];
            }
        }
#pragma unroll
        for (int mi = 0; mi < 4; ++mi)
#pragma unroll
            for (int ni = 0; ni < 2; ++ni) {
                acc[mi][ni] = __builtin_amdgcn_mfma_f32_16x16x32_bf16(
                    af[0][mi], bfr[0][ni], acc[mi][ni], 0, 0, 0);
                acc[mi][ni] = __builtin_amdgcn_mfma_f32_16x16x32_bf16(
                    af[1][mi], bfr[1][ni], acc[mi][ni], 0, 0, 0);
            }
        __syncthreads();   // drains next-tile gload_lds (vmcnt) + read hazard
        cur ^= 1;
    }

#pragma unroll
    for (int mi = 0; mi < 4; ++mi) {
        const int row = bm + mi * 16 + quad * 4;
#pragma unroll
        for (int ni = 0; ni < 2; ++ni) {
            const int col = bn + wave * 32 + ni * 16 + l16;
#pragma unroll
            for (int r = 0; r < 4; ++r) epi(row + r, col, acc[mi][ni][r]);
        }
    }
}

// Fused QKV projection: B rows = [Wq(2048) | Wk(128) | Wv(128)], N=2304.
// Q gets (1/sqrt(128))*log2(e) folded in (attention uses exp2).
__global__ __launch_bounds__(256) void gemm_qkv(const u16* __restrict__ A,
                                                const u16* __restrict__ B,
                                                u16* __restrict__ qb,
                                                u16* __restrict__ kb,
                                                u16* __restrict__ vtb) {
    gemm_core(A, B, 2048, blockIdx.x * 64, blockIdx.y * 128,
              [=](int row, int col, float v) {
                  if (col < 2048)
                      qb[(size_t)row * 2048 + col] = f2bf(v * 0.1275174313451427f);
                  else if (col < 2176)
                      kb[(size_t)row * 128 + (col - 2048)] = f2bf(v);
                  else
                      vtb[(size_t)(col - 2176) * VSTR + row] = f2bf(v);
              });
}

__global__ __launch_bounds__(256) void gemm_out(const u16* __restrict__ A,
                                                const u16* __restrict__ B,
                                                float* __restrict__ C) {
    gemm_core(A, B, 2048, blockIdx.x * 64, blockIdx.y * 128,
              [=](int row, int col, float v) {
                  C[(size_t)row * 2048 + col] = v;
              });
}

// ---------------- MQA flash attention, split-K (2 or 3), 32 keys/step -------
// r15 post-mortem: split-K=4 + __launch_bounds__(256,4) spilled — unified
// working set ~148 regs (84 VGPR + 64 AGPR acc) > 512/4=128 budget; Occ rose
// to 36% but scratch traffic made it WORSE (81us). Clean retest of the
// wave-coverage hypothesis at the max spill-free occupancy: split-K=3 ->
// grid (16,16,3) = 768 blocks = 3 blocks/CU = 3 waves/SIMD (3x148=444<=512),
// bound (256,3), no tail. 64 steps split 22/21/21. Needs ~75MB ws (r15
// proved >=93MB); guard falls back to split-K=2 (r13-identical).
// Structure otherwise r13: 32x32x16 swapped QK^T; P in registers via
// cvt_pk + permlane32_swap (T12); K+V double-buffered LDS (32KB); ONE
// barrier/step. Deferred softmax: P = exp2(s) (Q pre-scaled); fp32 partials
// + Lsum, normalized in combine.
__global__ __launch_bounds__(256, 3) void mqa_attn(const u16* __restrict__ Q,
                                                   const u16* __restrict__ Kmat,
                                                   const u16* __restrict__ Vt,
                                                   float* __restrict__ Oacc0,
                                                   float* __restrict__ OaccHi,
                                                   float* __restrict__ Lsum,
                                                   int nsplit) {
    __shared__ __align__(16) u16 Ks[2][4 * 32 * 32];  // [buf][d-chunk][key32][32 d] 8KB/buf
    __shared__ __align__(16) u16 Vts[2][128 * 32];    // [buf][d128][32 keys]       8KB/buf
    const int tid  = threadIdx.x;
    const int wave = tid >> 6, lane = tid & 63;
    const int l31 = lane & 31, hi = lane >> 5;
    const int h     = blockIdx.y;
    const int ksp   = blockIdx.z;
    const int qbase = blockIdx.x * 128 + wave * 32;
    // 64 total 32-key steps split as evenly as possible across nsplit
    const int base = 64 / nsplit, rem = 64 % nsplit;
    const int nsteps = base + (ksp < rem ? 1 : 0);
    const int kbase  = (ksp * base + (ksp < rem ? ksp : rem)) * 32;

    // Q as B-operand frags: lane holds Q[q = l31][c*16 + hi*8 + j]
    bf16x8 qf[8];
    {
        const u16* qptr = Q + (size_t)(qbase + l31) * 2048 + h * 128 + hi * 8;
#pragma unroll
        for (int c = 0; c < 8; ++c) qf[c] = *(const bf16x8*)(qptr + c * 16);
    }

    f32x16 acc[4];
#pragma unroll
    for (int dt = 0; dt < 4; ++dt) acc[dt] = (f32x16)(0.0f);
    float lsum = 0.f;

    auto stage = [&](int s, int buf) {
        const int k0 = kbase + s * 32;
        // K tile: 512 slots of 16B (kb4=slot>>7, row=(slot&127)>>2, cs=slot&3)
#pragma unroll
        for (int i = 0; i < 2; ++i) {
            const int slot = i * 256 + tid;
            const int kb4 = slot >> 7, win = slot & 127;
            const int row = win >> 2;
            GLOAD_LDS16(Kmat + (size_t)(k0 + row) * 128 + kb4 * 32 + sw_st(win & 3, row),
                        &Ks[buf][slot * 8]);
        }
        // V^T tile: 512 slots (row=slot>>2 over 128 d, cs=slot&3 over 32 keys)
#pragma unroll
        for (int i = 0; i < 2; ++i) {
            const int slot = i * 256 + tid;
            const int row = slot >> 2;
            GLOAD_LDS16(Vt + (size_t)row * VSTR + k0 + sw_st(slot & 3, row),
                        &Vts[buf][slot * 8]);
        }
    };

    stage(0, 0);
    __syncthreads();
    int cur = 0;

    for (int s = 0; s < nsteps; ++s) {
        if (s < nsteps - 1) stage(s + 1, cur ^ 1);

        // ---- S^T = K Q^T: one 8-MFMA chain over the 32-key tile ----
        f32x16 sv = (f32x16)(0.0f);
#pragma unroll
        for (int c = 0; c < 8; ++c) {
            const int ch = (c & 1) * 2 + hi;
            bf16x8 kf = *(const bf16x8*)&Ks[cur][(c >> 1) * 1024 + l31 * 32 + sw_rd(ch, l31)];
            sv = __builtin_amdgcn_mfma_f32_32x32x16_bf16(kf, qf[c], sv, 0, 0, 0);
        }

        // ---- P = exp2(S) packed in-register -> PV A-frags ----
        // lane holds S^T[key=(r&3)+8*(r>>2)+4*hi][q=l31]
        bf16x8 pa[2];  // [key chunk of 16]
        {
            float e[16];
#pragma unroll
            for (int r = 0; r < 16; ++r) {
                e[r] = exp2f(sv[r]);
                lsum += e[r];
            }
#pragma unroll
            for (int half = 0; half < 2; ++half) {
                unsigned a0 = cvtpk(e[half * 8 + 0], e[half * 8 + 1]);
                unsigned a1 = cvtpk(e[half * 8 + 2], e[half * 8 + 3]);
                unsigned b0 = cvtpk(e[half * 8 + 4], e[half * 8 + 5]);
                unsigned b1 = cvtpk(e[half * 8 + 6], e[half * 8 + 7]);
                pl32swap(a0, b0);
                pl32swap(a1, b1);
                uint4_v w = {a0, a1, b0, b1};
                pa[half] = __builtin_bit_cast(bf16x8, w);
            }
        }

        // ---- O += P V : 8 MFMA, 4 independent dt chains ----
#pragma unroll
        for (int kc = 0; kc < 2; ++kc) {
            const int ch = kc * 2 + hi;
#pragma unroll
            for (int dt = 0; dt < 4; ++dt) {
                const int row = dt * 32 + l31;  // d row
                bf16x8 vf = *(const bf16x8*)&Vts[cur][row * 32 + sw_rd(ch, row)];
                acc[dt] = __builtin_amdgcn_mfma_f32_32x32x16_bf16(pa[kc], vf, acc[dt], 0, 0, 0);
            }
        }
        __syncthreads();   // drains next-tile gload_lds + this tile's reads
        cur ^= 1;
    }

    // ---- epilogue: unnormalized fp32 partials + per-row sums ----
    float lrow = lsum + __shfl_xor(lsum, 32);
    float* __restrict__ Op = ksp ? (OaccHi + (size_t)(ksp - 1) * (4u << 20)) : Oacc0;
    if (lane < 32) Lsum[(size_t)ksp * 32768 + h * 2048 + qbase + l31] = lrow;
#pragma unroll
    for (int dt = 0; dt < 4; ++dt)
#pragma unroll
        for (int r = 0; r < 16; ++r) {
            const int qloc = (r & 3) + 8 * (r >> 2) + 4 * hi;
            Op[((size_t)h * 2048 + qbase + qloc) * 128 + dt * 32 + l31] = acc[dt][r];
        }
}

// combine: attn[q][h*128+d] = sum_s(Os)/sum_s(Ls), bf16. One float4 per thread.
__global__ __launch_bounds__(256) void attn_combine(const float* __restrict__ O0,
                                                    const float* __restrict__ OHi,
                                                    const float* __restrict__ L,
                                                    u16* __restrict__ attn,
                                                    int nsplit) {
    const int f = blockIdx.x * 256 + threadIdx.x;  // [0, 1M)
    const int d4 = f & 31, h = (f >> 5) & 15, q = f >> 9;
    const int li = h * 2048 + q;
    float lt = L[li];
    for (int s = 1; s < nsplit; ++s) lt += L[(size_t)s * 32768 + li];
    const float inv = 1.0f / lt;
    const int oi = li * 32 + d4;
    float4 a = ((const float4*)O0)[oi];
    for (int s = 1; s < nsplit; ++s) {
        const float4 b = ((const float4*)(OHi + (size_t)(s - 1) * (4u << 20)))[oi];
        a.x += b.x; a.y += b.y; a.z += b.z; a.w += b.w;
    }
    ushort4 r;
    r.x = f2bf(a.x * inv);
    r.y = f2bf(a.y * inv);
    r.z = f2bf(a.z * inv);
    r.w = f2bf(a.w * inv);
    ((ushort4*)attn)[f] = r;
}

// ---------------- orchestration ----------------
extern "C" void kernel_launch(void* const* d_in, const int* in_sizes, int n_in,
                              void* d_out, int out_size, void* d_ws, size_t ws_size,
                              hipStream_t stream) {
    const float* x  = (const float*)d_in[0];
    const float* Wq = (const float*)d_in[1];
    const float* Wk = (const float*)d_in[2];
    const float* Wv = (const float*)d_in[3];
    const float* Wo = (const float*)d_in[4];
    float* out = (float*)d_out;

    // Wqb/Wkb/Wvb contiguous: together a 2304x2048 bf16 B matrix for gemm_qkv.
    // Overlays (stream-ordered, deterministic):
    //   Oacc0:  [0,16MB)   -- xb+Wqb dead after gemm_qkv
    //   OaccHi: after attn buffer (~42.5MB) -- (nsplit-1) x 16MB partials
    //   Lsum:   after last partial. Peak: nsplit=2 -> ~59MB, nsplit=3 -> ~75MB.
    u16* ws   = (u16*)d_ws;
    u16* xb   = ws;                        // 2048x2048 bf16
    u16* Wqb  = xb  + (4 << 20);           // 2048x2048
    u16* Wkb  = Wqb + (4 << 20);           // 128x2048
    u16* Wvb  = Wkb + (256 << 10);         // 128x2048
    u16* Wob  = Wvb + (256 << 10);         // 2048x2048
    u16* qb   = Wob + (4 << 20);           // 2048x2048 (pre-scaled)
    u16* kb   = qb  + (4 << 20);           // 2048x128
    u16* vtb  = kb  + (256 << 10);         // 128xVSTR (V^T, padded rows)
    u16* attn = vtb + (512 << 10);         // 2048x2048 bf16
    float* Oacc0  = (float*)ws;            // 16 MB
    float* OaccHi = (float*)(attn + (4 << 20));   // (nsplit-1) x 16MB

    // split-K=3 raises resident waves to 3/SIMD (768 blocks, no spill at
    // bound 3); needs ~75MB workspace — else fall back to the r13-measured
    // split-K=2 layout.
    const int nsplit = (ws_size >= ((size_t)77 << 20)) ? 3 : 2;
    float* Lsum = OaccHi + (size_t)(nsplit - 1) * (4u << 20);  // nsplit x 32768 fp32

    cast_all<<<12800, 256, 0, stream>>>(x, Wq, Wk, Wv, Wo, xb, Wqb, Wkb, Wvb, Wob);

    gemm_qkv<<<dim3(32, 18), 256, 0, stream>>>(xb, Wqb, qb, kb, vtb);
    mqa_attn<<<dim3(16, 16, nsplit), 256, 0, stream>>>(qb, kb, vtb, Oacc0, OaccHi, Lsum,
                                                       nsplit);
    attn_combine<<<4096, 256, 0, stream>>>(Oacc0, OaccHi, Lsum, attn, nsplit);
    gemm_out<<<dim3(32, 16), 256, 0, stream>>>(attn, Wob, out);
}